// Round 12
// baseline (87.532 us; speedup 1.0000x reference)
//
#include <hip/hip_runtime.h>

#define BINW 64           // dsts per bin
#define CAP  1280         // max edges per bin (mean 1024, sigma ~32 -> +8 sigma)
#define EPB  4096         // edges per bin block (16 per thread)
#define MAXBINS 1024

__device__ __forceinline__ unsigned pack_bf16x2(float x, float y) {
    unsigned ux = __float_as_uint(x); ux += 0x7fffu + ((ux >> 16) & 1);
    unsigned uy = __float_as_uint(y); uy += 0x7fffu + ((uy >> 16) & 1);
    return (ux >> 16) | (uy & 0xffff0000u);
}

// Zero bin_cnt via kernel dispatch (hipMemsetAsync's fill path costs ~42us
// per graph replay for tiny fills — measured R10/R11).
__global__ __launch_bounds__(256) void k_zero(int* __restrict__ p, int n)
{
    int i = blockIdx.x * 256 + threadIdx.x;
    if (i < n) p[i] = 0;
}

// Bin edges by dst>>6: rank within (block,bin) via LDS cursor, reserve global
// segment, direct scatter. word = b(10) | src(16) | dlow(6).
__global__ __launch_bounds__(256) void k_bin(
    const int* __restrict__ src, const int* __restrict__ dst,
    int* __restrict__ bin_cnt, unsigned* __restrict__ binned,
    int n_edges, int nbins)
{
    __shared__ int cursor[MAXBINS], gpos[MAXBINS];
    const int t = threadIdx.x;
    const int e0 = blockIdx.x * EPB;

    for (int i = t; i < nbins; i += 256) cursor[i] = 0;
    __syncthreads();

    unsigned myw[16]; int myr[16];
#pragma unroll
    for (int k = 0; k < 16; ++k) {
        int e = e0 + k * 256 + t;
        myw[k] = 0xffffffffu;
        if (e < n_edges) {
            int d = dst[e], s = src[e];
            int b = d >> 6;
            myw[k] = ((unsigned)b << 22) | ((unsigned)s << 6) | (unsigned)(d & 63);
            myr[k] = atomicAdd(&cursor[b], 1);
        }
    }
    __syncthreads();
    for (int i = t; i < nbins; i += 256) {
        int c = cursor[i];
        gpos[i] = c ? atomicAdd(&bin_cnt[i * 16], c) : 0;
    }
    __syncthreads();
#pragma unroll
    for (int k = 0; k < 16; ++k) {
        unsigned w = myw[k];
        if (w != 0xffffffffu) {
            int b = w >> 22;
            binned[b * CAP + gpos[b] + myr[k]] = w & 0x3fffffu;
        }
    }
}

// hw16 = bf16(h @ Ww + bw). Wave = 16 rows x 64 cols; thread = 4 rows x 4 cols.
// Epilogue: per-(node,head) attention dots via 4-lane shfl_xor reduce.
__global__ __launch_bounds__(256) void k_proj(
    const float* __restrict__ h, const float* __restrict__ Ww,
    const float* __restrict__ bw, const float* __restrict__ Wa,
    const float* __restrict__ ba_p,
    unsigned short* __restrict__ hw16,
    float* __restrict__ asrc, float* __restrict__ adst, int n_nodes)
{
    __shared__ float ws[128 * 64];
#pragma unroll
    for (int i = 0; i < 8; ++i)
        ((float4*)ws)[i * 256 + threadIdx.x] = ((const float4*)Ww)[i * 256 + threadIdx.x];
    __syncthreads();

    const int lane = threadIdx.x & 63;
    const int wid  = threadIdx.x >> 6;
    const int cg   = lane & 15;     // cols 4cg .. 4cg+3
    const int rsub = lane >> 4;     // 0..3
    const int head = cg >> 2;
    const int row0 = (blockIdx.x * 4 + wid) * 16 + rsub * 4;
    if (row0 >= n_nodes) return;

    float acc[4][4];
#pragma unroll
    for (int r = 0; r < 4; ++r)
#pragma unroll
        for (int c = 0; c < 4; ++c) acc[r][c] = 0.f;

    const float* hrow = h + (size_t)row0 * 128;

    for (int k = 0; k < 128; k += 4) {
        float ha[4][4];
#pragma unroll
        for (int r = 0; r < 4; ++r)
            *(float4*)ha[r] = *(const float4*)(hrow + r * 128 + k);
#pragma unroll
        for (int kk = 0; kk < 4; ++kk) {
            float4 w4 = *(const float4*)(&ws[(k + kk) * 64 + cg * 4]);
#pragma unroll
            for (int r = 0; r < 4; ++r) {
                acc[r][0] = __fmaf_rn(ha[r][kk], w4.x, acc[r][0]);
                acc[r][1] = __fmaf_rn(ha[r][kk], w4.y, acc[r][1]);
                acc[r][2] = __fmaf_rn(ha[r][kk], w4.z, acc[r][2]);
                acc[r][3] = __fmaf_rn(ha[r][kk], w4.w, acc[r][3]);
            }
        }
    }
    const float4 b4 = *(const float4*)(bw + cg * 4);
    const int j0 = (cg & 3) * 4;
    const float4 waS = *(const float4*)(Wa + j0);
    const float4 waD = *(const float4*)(Wa + 16 + j0);
    const float ba = *ba_p;
#pragma unroll
    for (int r = 0; r < 4; ++r) {
        float4 o;
        o.x = acc[r][0] + b4.x;
        o.y = acc[r][1] + b4.y;
        o.z = acc[r][2] + b4.z;
        o.w = acc[r][3] + b4.w;
        const size_t idx = (size_t)(row0 + r) * 64 + cg * 4;
        uint2 p;
        p.x = pack_bf16x2(o.x, o.y);
        p.y = pack_bf16x2(o.z, o.w);
        *(uint2*)(hw16 + idx) = p;

        float pas = o.x * waS.x + o.y * waS.y + o.z * waS.z + o.w * waS.w;
        float pad = o.x * waD.x + o.y * waD.y + o.z * waD.z + o.w * waD.w;
        pas += __shfl_xor(pas, 1);
        pas += __shfl_xor(pas, 2);
        pad += __shfl_xor(pad, 1);
        pad += __shfl_xor(pad, 2);
        if ((cg & 3) == 0) {
            asrc[(row0 + r) * 4 + head] = pas;
            adst[(row0 + r) * 4 + head] = pad + ba;
        }
    }
}

// One block per bin: LDS counting-sort the bin's edges by dst, then gather
// directly from LDS-sorted edge words. Wave wid handles dsts wid+4*j, j<16.
__global__ __launch_bounds__(256) void k_gather(
    const int* __restrict__ bin_cnt, const unsigned* __restrict__ binned,
    const float* __restrict__ asrc, const float* __restrict__ adst,
    const unsigned short* __restrict__ hw16, float* __restrict__ out, int n_nodes)
{
    __shared__ unsigned data[CAP];
    __shared__ unsigned srt[CAP];
    __shared__ int hist[BINW], lstart[BINW], cursor[BINW];
    const int t = threadIdx.x;
    const int b = blockIdx.x;
    const int cnt = min(bin_cnt[b * 16], CAP);
    const int base = b * CAP;

    if (t < BINW) hist[t] = 0;
    __syncthreads();
    for (int i = t; i < cnt; i += 256) {
        unsigned w = binned[base + i];
        data[i] = w;
        atomicAdd(&hist[w & 63], 1);
    }
    __syncthreads();
    if (t < 64) {
        int v = hist[t];
        int x = v;
#pragma unroll
        for (int off = 1; off < 64; off <<= 1) {
            int n_ = __shfl_up(x, off);
            if (t >= off) x += n_;
        }
        lstart[t] = x - v;
        cursor[t] = x - v;
    }
    __syncthreads();
    for (int i = t; i < cnt; i += 256) {
        unsigned w = data[i];
        int pos = atomicAdd(&cursor[w & 63], 1);
        srt[pos] = w;
    }
    __syncthreads();

    const int lane = t & 63;
    const int wid  = t >> 6;
    const int head = lane >> 4;
    const int eloc = lane & 7;

    for (int j = 0; j < 16; ++j) {
        const int dlow = wid + 4 * j;
        const int d = b * BINW + dlow;
        if (d >= n_nodes) continue;
        const int start = lstart[dlow];
        const int cd = hist[dlow];
        if (cd <= 0) {
            out[(size_t)d * 64 + lane] = 0.f;
            continue;
        }
        const int end = start + cd;
        const float ad = adst[(unsigned)(d * 4 + head)];
        float acc = 0.f, den = 0.f;

        for (int i = start; i < end; i += 8) {
            int myi = i + eloc;
            int ld = (myi < end) ? myi : start;
            unsigned w = srt[ld];
            int s_p = (int)((w >> 6) & 0xffffu);
            float a = asrc[(unsigned)(s_p * 4 + head)] + ad;
            a = fmaxf(a, 0.01f * a);
            float ea = __expf(a);
            ea = (myi < end) ? ea : 0.f;
#pragma unroll
            for (int k = 0; k < 8; ++k) {
                int   s_k  = __shfl(s_p, k);
                float ea_k = __shfl(ea, k | (head << 4));
                den += ea_k;
                float hv = __uint_as_float((unsigned)hw16[(unsigned)(s_k * 64 + lane)] << 16);
                acc = __fmaf_rn(ea_k, hv, acc);
            }
        }
        out[(size_t)d * 64 + lane] = acc / den;
    }
}

extern "C" void kernel_launch(void* const* d_in, const int* in_sizes, int n_in,
                              void* d_out, int out_size, void* d_ws, size_t ws_size,
                              hipStream_t stream)
{
    const float* h  = (const float*)d_in[0];
    const float* Ww = (const float*)d_in[1];
    const float* bw = (const float*)d_in[2];
    const float* Wa = (const float*)d_in[3];
    const float* ba = (const float*)d_in[4];
    const int* src  = (const int*)d_in[5];
    const int* dst  = (const int*)d_in[6];

    const int n_nodes = in_sizes[0] / 128;
    const int n_edges = in_sizes[5];
    const int nbins = (n_nodes + BINW - 1) / BINW;   // 782

    // Workspace (4B words):
    // hw16[N*64] bf16 | asrc[N*4] | adst[N*4] | bin_cnt[nbins*16] | binned[nbins*CAP]
    unsigned short* hw16 = (unsigned short*)d_ws;
    float* asrc          = (float*)(hw16 + (size_t)n_nodes * 64);
    float* adst          = asrc + (size_t)n_nodes * 4;
    int* bin_cnt         = (int*)(adst + (size_t)n_nodes * 4);
    unsigned* binned     = (unsigned*)(bin_cnt + (size_t)nbins * 16);

    float* out = (float*)d_out;

    const int nzero = nbins * 16;
    k_zero<<<(nzero + 255) / 256, 256, 0, stream>>>(bin_cnt, nzero);

    const int bin_blocks = (n_edges + EPB - 1) / EPB;       // 196
    k_bin<<<bin_blocks, 256, 0, stream>>>(src, dst, bin_cnt, binned, n_edges, nbins);

    const int proj_blocks = (n_nodes + 63) / 64;            // 782
    k_proj<<<proj_blocks, 256, 0, stream>>>(h, Ww, bw, Wa, ba, hw16, asrc, adst, n_nodes);

    k_gather<<<nbins, 256, 0, stream>>>(bin_cnt, binned, asrc, adst, hw16, out, n_nodes);
}

// Round 13
// 81.631 us; speedup vs baseline: 1.0723x; 1.0723x over previous
//
#include <hip/hip_runtime.h>

#define BINW 64           // dsts per bin
#define CAP  1280         // max edges per bin (mean 1024, sigma ~32 -> +8 sigma)
#define EPB  4096         // edges per bin block (16 per thread)
#define MAXBINS 1024

__device__ __forceinline__ unsigned pack_bf16x2(float x, float y) {
    unsigned ux = __float_as_uint(x); ux += 0x7fffu + ((ux >> 16) & 1);
    unsigned uy = __float_as_uint(y); uy += 0x7fffu + ((uy >> 16) & 1);
    return (ux >> 16) | (uy & 0xffff0000u);
}

// Blocks [0, zblocks): zero bin_cnt. Blocks [zblocks, ...): hw16 = bf16(h@Ww+bw)
// with per-(node,head) attention-dot epilogue (4-lane shfl_xor reduce).
// Zeroing rides in this dispatch; the k_bin dispatch boundary orders it.
__global__ __launch_bounds__(256) void k_proj(
    const float* __restrict__ h, const float* __restrict__ Ww,
    const float* __restrict__ bw, const float* __restrict__ Wa,
    const float* __restrict__ ba_p,
    unsigned short* __restrict__ hw16,
    float* __restrict__ asrc, float* __restrict__ adst, int n_nodes,
    int* __restrict__ bin_cnt, int nzero, int zblocks)
{
    if ((int)blockIdx.x < zblocks) {
        int i = blockIdx.x * 256 + threadIdx.x;
        if (i < nzero) bin_cnt[i] = 0;
        return;
    }
    __shared__ float ws[128 * 64];
#pragma unroll
    for (int i = 0; i < 8; ++i)
        ((float4*)ws)[i * 256 + threadIdx.x] = ((const float4*)Ww)[i * 256 + threadIdx.x];
    __syncthreads();

    const int bid  = (int)blockIdx.x - zblocks;
    const int lane = threadIdx.x & 63;
    const int wid  = threadIdx.x >> 6;
    const int cg   = lane & 15;     // cols 4cg .. 4cg+3
    const int rsub = lane >> 4;     // 0..3
    const int head = cg >> 2;
    const int row0 = (bid * 4 + wid) * 16 + rsub * 4;
    if (row0 >= n_nodes) return;

    float acc[4][4];
#pragma unroll
    for (int r = 0; r < 4; ++r)
#pragma unroll
        for (int c = 0; c < 4; ++c) acc[r][c] = 0.f;

    const float* hrow = h + (size_t)row0 * 128;

    for (int k = 0; k < 128; k += 4) {
        float ha[4][4];
#pragma unroll
        for (int r = 0; r < 4; ++r)
            *(float4*)ha[r] = *(const float4*)(hrow + r * 128 + k);
#pragma unroll
        for (int kk = 0; kk < 4; ++kk) {
            float4 w4 = *(const float4*)(&ws[(k + kk) * 64 + cg * 4]);
#pragma unroll
            for (int r = 0; r < 4; ++r) {
                acc[r][0] = __fmaf_rn(ha[r][kk], w4.x, acc[r][0]);
                acc[r][1] = __fmaf_rn(ha[r][kk], w4.y, acc[r][1]);
                acc[r][2] = __fmaf_rn(ha[r][kk], w4.z, acc[r][2]);
                acc[r][3] = __fmaf_rn(ha[r][kk], w4.w, acc[r][3]);
            }
        }
    }
    const float4 b4 = *(const float4*)(bw + cg * 4);
    const int j0 = (cg & 3) * 4;
    const float4 waS = *(const float4*)(Wa + j0);
    const float4 waD = *(const float4*)(Wa + 16 + j0);
    const float ba = *ba_p;
#pragma unroll
    for (int r = 0; r < 4; ++r) {
        float4 o;
        o.x = acc[r][0] + b4.x;
        o.y = acc[r][1] + b4.y;
        o.z = acc[r][2] + b4.z;
        o.w = acc[r][3] + b4.w;
        const size_t idx = (size_t)(row0 + r) * 64 + cg * 4;
        uint2 p;
        p.x = pack_bf16x2(o.x, o.y);
        p.y = pack_bf16x2(o.z, o.w);
        *(uint2*)(hw16 + idx) = p;

        float pas = o.x * waS.x + o.y * waS.y + o.z * waS.z + o.w * waS.w;
        float pad = o.x * waD.x + o.y * waD.y + o.z * waD.z + o.w * waD.w;
        pas += __shfl_xor(pas, 1);
        pas += __shfl_xor(pas, 2);
        pad += __shfl_xor(pad, 1);
        pad += __shfl_xor(pad, 2);
        if ((cg & 3) == 0) {
            asrc[(row0 + r) * 4 + head] = pas;
            adst[(row0 + r) * 4 + head] = pad + ba;
        }
    }
}

// Bin edges by dst>>6: rank within (block,bin) via LDS cursor, reserve global
// segment, direct scatter. word = b(10) | src(16) | dlow(6).
__global__ __launch_bounds__(256) void k_bin(
    const int* __restrict__ src, const int* __restrict__ dst,
    int* __restrict__ bin_cnt, unsigned* __restrict__ binned,
    int n_edges, int nbins)
{
    __shared__ int cursor[MAXBINS], gpos[MAXBINS];
    const int t = threadIdx.x;
    const int e0 = blockIdx.x * EPB;

    for (int i = t; i < nbins; i += 256) cursor[i] = 0;
    __syncthreads();

    unsigned myw[16]; int myr[16];
#pragma unroll
    for (int k = 0; k < 16; ++k) {
        int e = e0 + k * 256 + t;
        myw[k] = 0xffffffffu;
        if (e < n_edges) {
            int d = dst[e], s = src[e];
            int b = d >> 6;
            myw[k] = ((unsigned)b << 22) | ((unsigned)s << 6) | (unsigned)(d & 63);
            myr[k] = atomicAdd(&cursor[b], 1);
        }
    }
    __syncthreads();
    for (int i = t; i < nbins; i += 256) {
        int c = cursor[i];
        gpos[i] = c ? atomicAdd(&bin_cnt[i * 16], c) : 0;
    }
    __syncthreads();
#pragma unroll
    for (int k = 0; k < 16; ++k) {
        unsigned w = myw[k];
        if (w != 0xffffffffu) {
            int b = w >> 22;
            binned[b * CAP + gpos[b] + myr[k]] = w & 0x3fffffu;
        }
    }
}

// One block (512 threads, 8 waves) per bin: LDS counting-sort by dst, then
// gather from LDS-sorted edges. Wave wid handles dsts wid + 8*j, j<8.
__global__ __launch_bounds__(512) void k_gather(
    const int* __restrict__ bin_cnt, const unsigned* __restrict__ binned,
    const float* __restrict__ asrc, const float* __restrict__ adst,
    const unsigned short* __restrict__ hw16, float* __restrict__ out, int n_nodes)
{
    __shared__ unsigned data[CAP];
    __shared__ unsigned srt[CAP];
    __shared__ int hist[BINW], lstart[BINW], cursor[BINW];
    const int t = threadIdx.x;
    const int b = blockIdx.x;
    const int cnt = min(bin_cnt[b * 16], CAP);
    const int base = b * CAP;

    if (t < BINW) hist[t] = 0;
    __syncthreads();
    for (int i = t; i < cnt; i += 512) {
        unsigned w = binned[base + i];
        data[i] = w;
        atomicAdd(&hist[w & 63], 1);
    }
    __syncthreads();
    if (t < 64) {
        int v = hist[t];
        int x = v;
#pragma unroll
        for (int off = 1; off < 64; off <<= 1) {
            int n_ = __shfl_up(x, off);
            if (t >= off) x += n_;
        }
        lstart[t] = x - v;
        cursor[t] = x - v;
    }
    __syncthreads();
    for (int i = t; i < cnt; i += 512) {
        unsigned w = data[i];
        int pos = atomicAdd(&cursor[w & 63], 1);
        srt[pos] = w;
    }
    __syncthreads();

    const int lane = t & 63;
    const int wid  = t >> 6;      // 0..7
    const int head = lane >> 4;
    const int eloc = lane & 7;

    for (int j = 0; j < 8; ++j) {
        const int dlow = wid + 8 * j;
        const int d = b * BINW + dlow;
        if (d >= n_nodes) continue;
        const int start = lstart[dlow];
        const int cd = hist[dlow];
        if (cd <= 0) {
            out[(size_t)d * 64 + lane] = 0.f;
            continue;
        }
        const int end = start + cd;
        const float ad = adst[(unsigned)(d * 4 + head)];
        float acc = 0.f, den = 0.f;

        for (int i = start; i < end; i += 8) {
            int myi = i + eloc;
            int ld = (myi < end) ? myi : start;
            unsigned w = srt[ld];
            int s_p = (int)((w >> 6) & 0xffffu);
            float a = asrc[(unsigned)(s_p * 4 + head)] + ad;
            a = fmaxf(a, 0.01f * a);
            float ea = __expf(a);
            ea = (myi < end) ? ea : 0.f;
#pragma unroll
            for (int k = 0; k < 8; ++k) {
                int   s_k  = __shfl(s_p, k);
                float ea_k = __shfl(ea, k | (head << 4));
                den += ea_k;
                float hv = __uint_as_float((unsigned)hw16[(unsigned)(s_k * 64 + lane)] << 16);
                acc = __fmaf_rn(ea_k, hv, acc);
            }
        }
        out[(size_t)d * 64 + lane] = acc / den;
    }
}

extern "C" void kernel_launch(void* const* d_in, const int* in_sizes, int n_in,
                              void* d_out, int out_size, void* d_ws, size_t ws_size,
                              hipStream_t stream)
{
    const float* h  = (const float*)d_in[0];
    const float* Ww = (const float*)d_in[1];
    const float* bw = (const float*)d_in[2];
    const float* Wa = (const float*)d_in[3];
    const float* ba = (const float*)d_in[4];
    const int* src  = (const int*)d_in[5];
    const int* dst  = (const int*)d_in[6];

    const int n_nodes = in_sizes[0] / 128;
    const int n_edges = in_sizes[5];
    const int nbins = (n_nodes + BINW - 1) / BINW;   // 782

    // Workspace (4B words):
    // hw16[N*64] bf16 | asrc[N*4] | adst[N*4] | bin_cnt[nbins*16] | binned[nbins*CAP]
    unsigned short* hw16 = (unsigned short*)d_ws;
    float* asrc          = (float*)(hw16 + (size_t)n_nodes * 64);
    float* adst          = asrc + (size_t)n_nodes * 4;
    int* bin_cnt         = (int*)(adst + (size_t)n_nodes * 4);
    unsigned* binned     = (unsigned*)(bin_cnt + (size_t)nbins * 16);

    float* out = (float*)d_out;

    const int nzero   = nbins * 16;
    const int zblocks = (nzero + 255) / 256;                // 49
    const int proj_blocks = (n_nodes + 63) / 64;            // 782
    k_proj<<<zblocks + proj_blocks, 256, 0, stream>>>(
        h, Ww, bw, Wa, ba, hw16, asrc, adst, n_nodes, bin_cnt, nzero, zblocks);

    const int bin_blocks = (n_edges + EPB - 1) / EPB;       // 196
    k_bin<<<bin_blocks, 256, 0, stream>>>(src, dst, bin_cnt, binned, n_edges, nbins);

    k_gather<<<nbins, 512, 0, stream>>>(bin_cnt, binned, asrc, adst, hw16, out, n_nodes);
}

// Round 14
// 68.529 us; speedup vs baseline: 1.2773x; 1.1912x over previous
//
#include <hip/hip_runtime.h>

#define BINW 64           // dsts per bin
#define CAP  1280         // max edges per bin (mean 1024, sigma ~32 -> +8 sigma)
#define EPB  8192         // edges per bin block (2 x 16 per thread)
#define SLOT 32           // slots per (bin, block) segment: mean 10.5, P(>32)~e^-21
#define MAXBINS 1024

__device__ __forceinline__ unsigned pack_bf16x2(float x, float y) {
    unsigned ux = __float_as_uint(x); ux += 0x7fffu + ((ux >> 16) & 1);
    unsigned uy = __float_as_uint(y); uy += 0x7fffu + ((uy >> 16) & 1);
    return (ux >> 16) | (uy & 0xffff0000u);
}

// Fused stage 1. Blocks [0, nbb): bin edges into deterministic slotted segments
// binned[(b*nbb+bb)*SLOT + rank]; percnt[bb][b] fully overwritten (no zeroing,
// no global atomics). Blocks [nbb, ...): proj GEMM + attention-dot epilogue.
__global__ __launch_bounds__(256) void k_s1(
    const float* __restrict__ h, const float* __restrict__ Ww,
    const float* __restrict__ bw, const float* __restrict__ Wa,
    const float* __restrict__ ba_p,
    const int* __restrict__ src, const int* __restrict__ dst,
    unsigned short* __restrict__ hw16,
    float* __restrict__ asrc, float* __restrict__ adst,
    int* __restrict__ percnt, unsigned* __restrict__ binned,
    int n_nodes, int n_edges, int nbins, int nbb)
{
    const int t = threadIdx.x;
    if ((int)blockIdx.x < nbb) {
        // ---------------- bin path ----------------
        __shared__ int cursor[MAXBINS];
        const int bb = blockIdx.x;
        for (int i = t; i < nbins; i += 256) cursor[i] = 0;
        __syncthreads();
#pragma unroll
        for (int half = 0; half < 2; ++half) {
            const int e0 = bb * EPB + half * (EPB / 2);
            unsigned myw[16]; int myr[16];
#pragma unroll
            for (int k = 0; k < 16; ++k) {
                int e = e0 + k * 256 + t;
                myw[k] = 0xffffffffu;
                if (e < n_edges) {
                    int d = dst[e], s = src[e];
                    int b = d >> 6;
                    myw[k] = ((unsigned)b << 22) | ((unsigned)s << 6) | (unsigned)(d & 63);
                    myr[k] = atomicAdd(&cursor[b], 1);
                }
            }
#pragma unroll
            for (int k = 0; k < 16; ++k) {
                unsigned w = myw[k];
                if (w != 0xffffffffu && myr[k] < SLOT) {
                    int b = w >> 22;
                    binned[((unsigned)b * nbb + bb) * SLOT + myr[k]] = w & 0x3fffffu;
                }
            }
        }
        __syncthreads();
        for (int i = t; i < nbins; i += 256)
            percnt[bb * nbins + i] = min(cursor[i], SLOT);
        return;
    }
    // ---------------- proj path ----------------
    __shared__ float ws[128 * 64];
#pragma unroll
    for (int i = 0; i < 8; ++i)
        ((float4*)ws)[i * 256 + t] = ((const float4*)Ww)[i * 256 + t];
    __syncthreads();

    const int bid  = (int)blockIdx.x - nbb;
    const int lane = t & 63;
    const int wid  = t >> 6;
    const int cg   = lane & 15;     // cols 4cg .. 4cg+3
    const int rsub = lane >> 4;     // 0..3
    const int head = cg >> 2;
    const int row0 = (bid * 4 + wid) * 16 + rsub * 4;
    if (row0 >= n_nodes) return;

    float acc[4][4];
#pragma unroll
    for (int r = 0; r < 4; ++r)
#pragma unroll
        for (int c = 0; c < 4; ++c) acc[r][c] = 0.f;

    const float* hrow = h + (size_t)row0 * 128;

    for (int k = 0; k < 128; k += 4) {
        float ha[4][4];
#pragma unroll
        for (int r = 0; r < 4; ++r)
            *(float4*)ha[r] = *(const float4*)(hrow + r * 128 + k);
#pragma unroll
        for (int kk = 0; kk < 4; ++kk) {
            float4 w4 = *(const float4*)(&ws[(k + kk) * 64 + cg * 4]);
#pragma unroll
            for (int r = 0; r < 4; ++r) {
                acc[r][0] = __fmaf_rn(ha[r][kk], w4.x, acc[r][0]);
                acc[r][1] = __fmaf_rn(ha[r][kk], w4.y, acc[r][1]);
                acc[r][2] = __fmaf_rn(ha[r][kk], w4.z, acc[r][2]);
                acc[r][3] = __fmaf_rn(ha[r][kk], w4.w, acc[r][3]);
            }
        }
    }
    const float4 b4 = *(const float4*)(bw + cg * 4);
    const int j0 = (cg & 3) * 4;
    const float4 waS = *(const float4*)(Wa + j0);
    const float4 waD = *(const float4*)(Wa + 16 + j0);
    const float ba = *ba_p;
#pragma unroll
    for (int r = 0; r < 4; ++r) {
        float4 o;
        o.x = acc[r][0] + b4.x;
        o.y = acc[r][1] + b4.y;
        o.z = acc[r][2] + b4.z;
        o.w = acc[r][3] + b4.w;
        const size_t idx = (size_t)(row0 + r) * 64 + cg * 4;
        uint2 p;
        p.x = pack_bf16x2(o.x, o.y);
        p.y = pack_bf16x2(o.z, o.w);
        *(uint2*)(hw16 + idx) = p;

        float pas = o.x * waS.x + o.y * waS.y + o.z * waS.z + o.w * waS.w;
        float pad = o.x * waD.x + o.y * waD.y + o.z * waD.z + o.w * waD.w;
        pas += __shfl_xor(pas, 1);
        pas += __shfl_xor(pas, 2);
        pad += __shfl_xor(pad, 1);
        pad += __shfl_xor(pad, 2);
        if ((cg & 3) == 0) {
            asrc[(row0 + r) * 4 + head] = pas;
            adst[(row0 + r) * 4 + head] = pad + ba;
        }
    }
}

// One block (512 thr) per bin: scan 98 segment counts, compact segments into
// LDS, counting-sort by dst, gather. Wave wid handles dsts wid + 8*j, j<8.
__global__ __launch_bounds__(512) void k_gather(
    const int* __restrict__ percnt, const unsigned* __restrict__ binned,
    const float* __restrict__ asrc, const float* __restrict__ adst,
    const unsigned short* __restrict__ hw16, float* __restrict__ out,
    int n_nodes, int nbins, int nbb)
{
    __shared__ int seg_off[136];
    __shared__ unsigned data[CAP], srt[CAP];
    __shared__ int hist[BINW], lstart[BINW], cursor[BINW];
    const int t = threadIdx.x;
    const int b = blockIdx.x;
    const int lane = t & 63;
    const int wid  = t >> 6;      // 0..7

    if (t < 64) {
        int carry = 0;
        for (int base = 0; base < nbb; base += 64) {
            int i = base + t;
            int v = (i < nbb) ? percnt[i * nbins + b] : 0;
            int x = v;
#pragma unroll
            for (int off = 1; off < 64; off <<= 1) {
                int n_ = __shfl_up(x, off);
                if (t >= off) x += n_;
            }
            if (i < nbb) seg_off[i] = carry + x - v;
            carry += __shfl(x, 63);
        }
        if (t == 0) seg_off[nbb] = carry;
    }
    if (t < BINW) hist[t] = 0;
    __syncthreads();
    const int cnt = min(seg_off[nbb], CAP);

    for (int bb = wid; bb < nbb; bb += 8) {
        int o0 = seg_off[bb];
        int c  = seg_off[bb + 1] - o0;
        if (lane < c && o0 + lane < CAP)
            data[o0 + lane] = binned[((unsigned)b * nbb + bb) * SLOT + lane];
    }
    __syncthreads();
    for (int i = t; i < cnt; i += 512)
        atomicAdd(&hist[data[i] & 63], 1);
    __syncthreads();
    if (t < 64) {
        int v = hist[t];
        int x = v;
#pragma unroll
        for (int off = 1; off < 64; off <<= 1) {
            int n_ = __shfl_up(x, off);
            if (t >= off) x += n_;
        }
        lstart[t] = x - v;
        cursor[t] = x - v;
    }
    __syncthreads();
    for (int i = t; i < cnt; i += 512) {
        unsigned w = data[i];
        int pos = atomicAdd(&cursor[w & 63], 1);
        srt[pos] = w;
    }
    __syncthreads();

    const int head = lane >> 4;
    const int eloc = lane & 7;

    for (int j = 0; j < 8; ++j) {
        const int dlow = wid + 8 * j;
        const int d = b * BINW + dlow;
        if (d >= n_nodes) continue;
        const int start = lstart[dlow];
        const int cd = hist[dlow];
        if (cd <= 0) {
            out[(size_t)d * 64 + lane] = 0.f;
            continue;
        }
        const int end = start + cd;
        const float ad = adst[(unsigned)(d * 4 + head)];
        float acc = 0.f, den = 0.f;

        for (int i = start; i < end; i += 8) {
            int myi = i + eloc;
            int ld = (myi < end) ? myi : start;
            unsigned w = srt[ld];
            int s_p = (int)((w >> 6) & 0xffffu);
            float a = asrc[(unsigned)(s_p * 4 + head)] + ad;
            a = fmaxf(a, 0.01f * a);
            float ea = __expf(a);
            ea = (myi < end) ? ea : 0.f;
#pragma unroll
            for (int k = 0; k < 8; ++k) {
                int   s_k  = __shfl(s_p, k);
                float ea_k = __shfl(ea, k | (head << 4));
                den += ea_k;
                float hv = __uint_as_float((unsigned)hw16[(unsigned)(s_k * 64 + lane)] << 16);
                acc = __fmaf_rn(ea_k, hv, acc);
            }
        }
        out[(size_t)d * 64 + lane] = acc / den;
    }
}

extern "C" void kernel_launch(void* const* d_in, const int* in_sizes, int n_in,
                              void* d_out, int out_size, void* d_ws, size_t ws_size,
                              hipStream_t stream)
{
    const float* h  = (const float*)d_in[0];
    const float* Ww = (const float*)d_in[1];
    const float* bw = (const float*)d_in[2];
    const float* Wa = (const float*)d_in[3];
    const float* ba = (const float*)d_in[4];
    const int* src  = (const int*)d_in[5];
    const int* dst  = (const int*)d_in[6];

    const int n_nodes = in_sizes[0] / 128;
    const int n_edges = in_sizes[5];
    const int nbins = (n_nodes + BINW - 1) / BINW;   // 782
    const int nbb   = (n_edges + EPB - 1) / EPB;     // 98

    // Workspace (4B words):
    // hw16[N*64] bf16 | asrc[N*4] | adst[N*4] | percnt[nbb*nbins] |
    // binned[nbins*nbb*SLOT]
    unsigned short* hw16 = (unsigned short*)d_ws;
    float* asrc          = (float*)(hw16 + (size_t)n_nodes * 64);
    float* adst          = asrc + (size_t)n_nodes * 4;
    int* percnt          = (int*)(adst + (size_t)n_nodes * 4);
    unsigned* binned     = (unsigned*)(percnt + (size_t)nbb * nbins);

    float* out = (float*)d_out;

    const int proj_blocks = (n_nodes + 63) / 64;            // 782
    k_s1<<<nbb + proj_blocks, 256, 0, stream>>>(
        h, Ww, bw, Wa, ba, src, dst, hw16, asrc, adst, percnt, binned,
        n_nodes, n_edges, nbins, nbb);

    k_gather<<<nbins, 512, 0, stream>>>(
        percnt, binned, asrc, adst, hw16, out, n_nodes, nbins, nbb);
}

// Round 15
// 65.567 us; speedup vs baseline: 1.3350x; 1.0452x over previous
//
#include <hip/hip_runtime.h>

#define BINW 64           // dsts per bin
#define CAP  1280         // max edges per bin (mean 1024, sigma ~32 -> +8 sigma)
#define EPB  8192         // edges per bin block (2 x 16 per thread)
#define SLOT 32           // slots per (bin, block) segment: mean 10.5, P(>32)~e^-21
#define MAXBINS 1024

__device__ __forceinline__ unsigned pack_bf16x2(float x, float y) {
    unsigned ux = __float_as_uint(x); ux += 0x7fffu + ((ux >> 16) & 1);
    unsigned uy = __float_as_uint(y); uy += 0x7fffu + ((uy >> 16) & 1);
    return (ux >> 16) | (uy & 0xffff0000u);
}

// Fused stage 1. Blocks [0, nbb): bin edges into deterministic slotted segments
// binned[(b*nbb+bb)*SLOT + rank]; percnt[bb][b] fully overwritten (no zeroing,
// no global atomics). Blocks [nbb, ...): proj GEMM + attention-dot epilogue.
__global__ __launch_bounds__(256) void k_s1(
    const float* __restrict__ h, const float* __restrict__ Ww,
    const float* __restrict__ bw, const float* __restrict__ Wa,
    const float* __restrict__ ba_p,
    const int* __restrict__ src, const int* __restrict__ dst,
    unsigned short* __restrict__ hw16,
    float* __restrict__ asrc, float* __restrict__ adst,
    int* __restrict__ percnt, unsigned* __restrict__ binned,
    int n_nodes, int n_edges, int nbins, int nbb)
{
    const int t = threadIdx.x;
    if ((int)blockIdx.x < nbb) {
        // ---------------- bin path ----------------
        __shared__ int cursor[MAXBINS];
        const int bb = blockIdx.x;
        for (int i = t; i < nbins; i += 256) cursor[i] = 0;
        __syncthreads();
#pragma unroll
        for (int half = 0; half < 2; ++half) {
            const int e0 = bb * EPB + half * (EPB / 2);
            unsigned myw[16]; int myr[16];
#pragma unroll
            for (int k = 0; k < 16; ++k) {
                int e = e0 + k * 256 + t;
                myw[k] = 0xffffffffu;
                if (e < n_edges) {
                    int d = dst[e], s = src[e];
                    int b = d >> 6;
                    myw[k] = ((unsigned)b << 22) | ((unsigned)s << 6) | (unsigned)(d & 63);
                    myr[k] = atomicAdd(&cursor[b], 1);
                }
            }
#pragma unroll
            for (int k = 0; k < 16; ++k) {
                unsigned w = myw[k];
                if (w != 0xffffffffu && myr[k] < SLOT) {
                    int b = w >> 22;
                    binned[((unsigned)b * nbb + bb) * SLOT + myr[k]] = w & 0x3fffffu;
                }
            }
        }
        __syncthreads();
        for (int i = t; i < nbins; i += 256)
            percnt[bb * nbins + i] = min(cursor[i], SLOT);
        return;
    }
    // ---------------- proj path ----------------
    __shared__ float ws[128 * 64];
#pragma unroll
    for (int i = 0; i < 8; ++i)
        ((float4*)ws)[i * 256 + t] = ((const float4*)Ww)[i * 256 + t];
    __syncthreads();

    const int bid  = (int)blockIdx.x - nbb;
    const int lane = t & 63;
    const int wid  = t >> 6;
    const int cg   = lane & 15;     // cols 4cg .. 4cg+3
    const int rsub = lane >> 4;     // 0..3
    const int head = cg >> 2;
    const int row0 = (bid * 4 + wid) * 16 + rsub * 4;
    if (row0 >= n_nodes) return;

    float acc[4][4];
#pragma unroll
    for (int r = 0; r < 4; ++r)
#pragma unroll
        for (int c = 0; c < 4; ++c) acc[r][c] = 0.f;

    const float* hrow = h + (size_t)row0 * 128;

    for (int k = 0; k < 128; k += 4) {
        float ha[4][4];
#pragma unroll
        for (int r = 0; r < 4; ++r)
            *(float4*)ha[r] = *(const float4*)(hrow + r * 128 + k);
#pragma unroll
        for (int kk = 0; kk < 4; ++kk) {
            float4 w4 = *(const float4*)(&ws[(k + kk) * 64 + cg * 4]);
#pragma unroll
            for (int r = 0; r < 4; ++r) {
                acc[r][0] = __fmaf_rn(ha[r][kk], w4.x, acc[r][0]);
                acc[r][1] = __fmaf_rn(ha[r][kk], w4.y, acc[r][1]);
                acc[r][2] = __fmaf_rn(ha[r][kk], w4.z, acc[r][2]);
                acc[r][3] = __fmaf_rn(ha[r][kk], w4.w, acc[r][3]);
            }
        }
    }
    const float4 b4 = *(const float4*)(bw + cg * 4);
    const int j0 = (cg & 3) * 4;
    const float4 waS = *(const float4*)(Wa + j0);
    const float4 waD = *(const float4*)(Wa + 16 + j0);
    const float ba = *ba_p;
#pragma unroll
    for (int r = 0; r < 4; ++r) {
        float4 o;
        o.x = acc[r][0] + b4.x;
        o.y = acc[r][1] + b4.y;
        o.z = acc[r][2] + b4.z;
        o.w = acc[r][3] + b4.w;
        const size_t idx = (size_t)(row0 + r) * 64 + cg * 4;
        uint2 p;
        p.x = pack_bf16x2(o.x, o.y);
        p.y = pack_bf16x2(o.z, o.w);
        *(uint2*)(hw16 + idx) = p;

        float pas = o.x * waS.x + o.y * waS.y + o.z * waS.z + o.w * waS.w;
        float pad = o.x * waD.x + o.y * waD.y + o.z * waD.z + o.w * waD.w;
        pas += __shfl_xor(pas, 1);
        pas += __shfl_xor(pas, 2);
        pad += __shfl_xor(pad, 1);
        pad += __shfl_xor(pad, 2);
        if ((cg & 3) == 0) {
            asrc[(row0 + r) * 4 + head] = pas;
            adst[(row0 + r) * 4 + head] = pad + ba;
        }
    }
}

// One block (1024 thr, 16 waves) per bin. Compact-load fuses the dst-histogram:
// the hist atomicAdd's return value is the within-dst rank, packed into the
// word's free high bits (22+), so the scatter pass needs no second atomic.
// Wave wid handles 2 segments per round (lane<32 / lane>=32); gather: wave wid
// covers dsts wid + 16*j, j<4.
__global__ __launch_bounds__(1024) void k_gather(
    const int* __restrict__ percnt, const unsigned* __restrict__ binned,
    const float* __restrict__ asrc, const float* __restrict__ adst,
    const unsigned short* __restrict__ hw16, float* __restrict__ out,
    int n_nodes, int nbins, int nbb)
{
    __shared__ int seg_off[136];
    __shared__ unsigned data[CAP], srt[CAP];
    __shared__ int hist[BINW], lstart[BINW];
    const int t = threadIdx.x;
    const int b = blockIdx.x;
    const int lane = t & 63;
    const int wid  = t >> 6;      // 0..15

    if (t < BINW) hist[t] = 0;
    if (t >= 64 && t < 128) {
        const int tt = t - 64;
        int carry = 0;
        for (int base = 0; base < nbb; base += 64) {
            int i = base + tt;
            int v = (i < nbb) ? percnt[i * nbins + b] : 0;
            int x = v;
#pragma unroll
            for (int off = 1; off < 64; off <<= 1) {
                int n_ = __shfl_up(x, off);
                if (tt >= off) x += n_;
            }
            if (i < nbb) seg_off[i] = carry + x - v;
            carry += __shfl(x, 63);
        }
        if (tt == 0) seg_off[nbb] = carry;
    }
    __syncthreads();
    const int cnt = min(seg_off[nbb], CAP);

    // compact-load 2 segments/wave/round + fused hist-rank
    const int half = lane >> 5;          // 0/1
    const int sl   = lane & 31;          // slot within segment
    for (int bb0 = wid * 2 + half; bb0 < nbb; bb0 += 32) {
        int o0 = seg_off[bb0];
        int c  = seg_off[bb0 + 1] - o0;
        if (sl < c && o0 + sl < CAP) {
            unsigned w = binned[((unsigned)b * nbb + bb0) * SLOT + sl];
            unsigned r = (unsigned)atomicAdd(&hist[w & 63], 1);
            data[o0 + sl] = w | (r << 22);
        }
    }
    __syncthreads();
    if (t < 64) {
        int v = hist[t];
        int x = v;
#pragma unroll
        for (int off = 1; off < 64; off <<= 1) {
            int n_ = __shfl_up(x, off);
            if (t >= off) x += n_;
        }
        lstart[t] = x - v;
    }
    __syncthreads();
    for (int i = t; i < cnt; i += 1024) {
        unsigned w = data[i];
        srt[lstart[w & 63] + (w >> 22)] = w;
    }
    __syncthreads();

    const int head = lane >> 4;
    const int eloc = lane & 7;

    for (int j = 0; j < 4; ++j) {
        const int dlow = wid + 16 * j;
        const int d = b * BINW + dlow;
        if (d >= n_nodes) continue;
        const int start = lstart[dlow];
        const int cd = hist[dlow];
        if (cd <= 0) {
            out[(size_t)d * 64 + lane] = 0.f;
            continue;
        }
        const int end = start + cd;
        const float ad = adst[(unsigned)(d * 4 + head)];
        float acc = 0.f, den = 0.f;

        for (int i = start; i < end; i += 8) {
            int myi = i + eloc;
            int ld = (myi < end) ? myi : start;
            unsigned w = srt[ld];
            int s_p = (int)((w >> 6) & 0xffffu);
            float a = asrc[(unsigned)(s_p * 4 + head)] + ad;
            a = fmaxf(a, 0.01f * a);
            float ea = __expf(a);
            ea = (myi < end) ? ea : 0.f;
#pragma unroll
            for (int k = 0; k < 8; ++k) {
                int   s_k  = __shfl(s_p, k);
                float ea_k = __shfl(ea, k | (head << 4));
                den += ea_k;
                float hv = __uint_as_float((unsigned)hw16[(unsigned)(s_k * 64 + lane)] << 16);
                acc = __fmaf_rn(ea_k, hv, acc);
            }
        }
        out[(size_t)d * 64 + lane] = acc / den;
    }
}

extern "C" void kernel_launch(void* const* d_in, const int* in_sizes, int n_in,
                              void* d_out, int out_size, void* d_ws, size_t ws_size,
                              hipStream_t stream)
{
    const float* h  = (const float*)d_in[0];
    const float* Ww = (const float*)d_in[1];
    const float* bw = (const float*)d_in[2];
    const float* Wa = (const float*)d_in[3];
    const float* ba = (const float*)d_in[4];
    const int* src  = (const int*)d_in[5];
    const int* dst  = (const int*)d_in[6];

    const int n_nodes = in_sizes[0] / 128;
    const int n_edges = in_sizes[5];
    const int nbins = (n_nodes + BINW - 1) / BINW;   // 782
    const int nbb   = (n_edges + EPB - 1) / EPB;     // 98

    // Workspace (4B words):
    // hw16[N*64] bf16 | asrc[N*4] | adst[N*4] | percnt[nbb*nbins] |
    // binned[nbins*nbb*SLOT]
    unsigned short* hw16 = (unsigned short*)d_ws;
    float* asrc          = (float*)(hw16 + (size_t)n_nodes * 64);
    float* adst          = asrc + (size_t)n_nodes * 4;
    int* percnt          = (int*)(adst + (size_t)n_nodes * 4);
    unsigned* binned     = (unsigned*)(percnt + (size_t)nbb * nbins);

    float* out = (float*)d_out;

    const int proj_blocks = (n_nodes + 63) / 64;            // 782
    k_s1<<<nbb + proj_blocks, 256, 0, stream>>>(
        h, Ww, bw, Wa, ba, src, dst, hw16, asrc, adst, percnt, binned,
        n_nodes, n_edges, nbins, nbb);

    k_gather<<<nbins, 1024, 0, stream>>>(
        percnt, binned, asrc, adst, hw16, out, n_nodes, nbins, nbb);
}